// Round 1
// baseline (438.841 us; speedup 1.0000x reference)
//
#include <hip/hip_runtime.h>
#include <hip/hip_bf16.h>

// slotGATConv: N=20000 nodes, E=320000 edges, 4 ntypes x 64 in, 4 heads x 32 out,
// 8 edge types x 64 edge feats. All f32.

#define N_NTYPE 4
#define IN_F    64
#define OUT_F   32
#define HEADS   4
#define EDGE_F  64
#define N_ETYPE 8
#define SLOPE   0.2f
#define NPB     8     // nodes per block in k_node

// ---------------- Phase A: per-node linear + attention dots ----------------
// ft[n, h, t*32+o] = sum_i feat[n, t*64+i] * fc[t, i, h*32+o]
// el[n,h] = sum_k ft[n,h,k]*attn_l[h,k];  er likewise.
__global__ __launch_bounds__(128) void k_node(
    const float* __restrict__ feat, const float* __restrict__ fc,
    const float* __restrict__ attn_l, const float* __restrict__ attn_r,
    float* __restrict__ ft, float* __restrict__ el, float* __restrict__ er, int N)
{
    int j  = threadIdx.x;            // 0..127 -> (h,o)
    int n0 = blockIdx.x * NPB;
    __shared__ float sf[NPB * 256];

    #pragma unroll
    for (int nn = 0; nn < NPB; ++nn) {
        int n = n0 + nn;
        if (n < N) {
            sf[nn*256 + j]       = feat[(size_t)n*256 + j];
            sf[nn*256 + 128 + j] = feat[(size_t)n*256 + 128 + j];
        }
    }
    __syncthreads();

    float vals[NPB][N_NTYPE];
    #pragma unroll
    for (int t = 0; t < N_NTYPE; ++t) {
        float acc[NPB];
        #pragma unroll
        for (int nn = 0; nn < NPB; ++nn) acc[nn] = 0.f;
        const float* fcol = fc + t*IN_F*128 + j;   // fc[t, i, j], stride 128 over i
        #pragma unroll 8
        for (int i = 0; i < IN_F; ++i) {
            float w = fcol[i*128];
            #pragma unroll
            for (int nn = 0; nn < NPB; ++nn)
                acc[nn] = fmaf(sf[nn*256 + t*64 + i], w, acc[nn]);
        }
        #pragma unroll
        for (int nn = 0; nn < NPB; ++nn) vals[nn][t] = acc[nn];
    }

    int h = j >> 5, o = j & 31;
    float al[N_NTYPE], ar[N_NTYPE];
    #pragma unroll
    for (int t = 0; t < N_NTYPE; ++t) {
        al[t] = attn_l[h*128 + t*32 + o];
        ar[t] = attn_r[h*128 + t*32 + o];
    }

    #pragma unroll
    for (int nn = 0; nn < NPB; ++nn) {
        int n = n0 + nn;
        if (n >= N) continue;
        #pragma unroll
        for (int t = 0; t < N_NTYPE; ++t)
            ft[(size_t)n*512 + h*128 + t*32 + o] = vals[nn][t];
        float pl = 0.f, pr = 0.f;
        #pragma unroll
        for (int t = 0; t < N_NTYPE; ++t) {
            pl = fmaf(vals[nn][t], al[t], pl);
            pr = fmaf(vals[nn][t], ar[t], pr);
        }
        // reduce across the 32 lanes sharing head h (xor masks stay in 32-group)
        #pragma unroll
        for (int m = 16; m >= 1; m >>= 1) {
            pl += __shfl_xor(pl, m);
            pr += __shfl_xor(pr, m);
        }
        if (o == 0) { el[n*4 + h] = pl; er[n*4 + h] = pr; }
    }
}

// ---------------- Phase B: edge-type attention table (8 x 4) ----------------
__global__ void k_ee(const float* __restrict__ edge_emb, const float* __restrict__ w_e,
                     const float* __restrict__ attn_e, float* __restrict__ ee_type)
{
    int tid = threadIdx.x;         // 256 threads = 8 etypes x 32 lanes
    int et = tid >> 5, lane = tid & 31;
    float p[HEADS] = {0.f, 0.f, 0.f, 0.f};
    for (int f0 = 0; f0 < 2; ++f0) {
        int f = lane + f0*32;
        #pragma unroll
        for (int h = 0; h < HEADS; ++h) {
            float proj = 0.f;
            for (int c = 0; c < EDGE_F; ++c)
                proj = fmaf(edge_emb[et*EDGE_F + c], w_e[c*256 + h*64 + f], proj);
            p[h] = fmaf(proj, attn_e[h*64 + f], p[h]);
        }
    }
    #pragma unroll
    for (int m = 16; m >= 1; m >>= 1)
        #pragma unroll
        for (int h = 0; h < HEADS; ++h) p[h] += __shfl_xor(p[h], m);
    if (lane == 0)
        #pragma unroll
        for (int h = 0; h < HEADS; ++h) ee_type[et*4 + h] = p[h];
}

// ---------------- Phase C: edge logits, exp, segment-sum, dst histogram ----
__global__ void k_edge(const int* __restrict__ src, const int* __restrict__ dst,
                       const int* __restrict__ ef,
                       const float* __restrict__ el, const float* __restrict__ er,
                       const float* __restrict__ ee_type,
                       float* __restrict__ ex, float* __restrict__ s,
                       int* __restrict__ cnt, int E)
{
    int e = blockIdx.x * 256 + threadIdx.x;
    if (e >= E) return;
    int sN = src[e], dN = dst[e], t = ef[e];
    atomicAdd(&cnt[dN], 1);
    #pragma unroll
    for (int h = 0; h < HEADS; ++h) {
        float l = el[sN*4 + h] + er[dN*4 + h] + ee_type[t*4 + h];
        l = (l > 0.f) ? l : SLOPE * l;
        float x = __expf(l);
        ex[(size_t)e*4 + h] = x;
        atomicAdd(&s[dN*4 + h], x);
    }
}

// ---------------- Phase D: exclusive scan of counts (single block) ---------
__global__ void k_scan(const int* __restrict__ cnt, int* __restrict__ offs,
                       int* __restrict__ pos, int N)
{
    int tid = threadIdx.x;                 // 256 threads
    int chunk = (N + 255) / 256;
    int start = tid * chunk;
    int end   = min(start + chunk, N);
    int tsum = 0;
    for (int i = start; i < end; ++i) tsum += cnt[i];
    int lane = tid & 63, wv = tid >> 6;
    int v = tsum;
    #pragma unroll
    for (int d = 1; d < 64; d <<= 1) {
        int u = __shfl_up(v, d);
        if (lane >= d) v += u;
    }
    __shared__ int ws4[4];
    if (lane == 63) ws4[wv] = v;
    __syncthreads();
    int base = 0;
    for (int w = 0; w < wv; ++w) base += ws4[w];
    int run = base + v - tsum;             // exclusive prefix of this chunk
    for (int i = start; i < end; ++i) {
        offs[i] = run; pos[i] = run; run += cnt[i];
    }
    if (tid == 255) offs[N] = run;         // == E
}

// ---------------- Phase E: scatter edge ids into CSR order -----------------
__global__ void k_scatter(const int* __restrict__ dst, int* __restrict__ pos,
                          int* __restrict__ order, int E)
{
    int e = blockIdx.x * 256 + threadIdx.x;
    if (e >= E) return;
    int p = atomicAdd(&pos[dst[e]], 1);
    order[p] = e;
}

// ---------------- Phase F: per-dst aggregation -----------------------------
// rst[n,h,j] = sum_{e in in(n)} (ex[e,h]/(s[n,h]+1e-16)) * ft[src[e], h, j]
__global__ __launch_bounds__(128) void k_agg(
    const int* __restrict__ offs, const int* __restrict__ order,
    const int* __restrict__ src, const float* __restrict__ ex,
    const float* __restrict__ s, const float* __restrict__ ft,
    float* __restrict__ out)
{
    int n = blockIdx.x;
    int j = threadIdx.x;                   // 0..127
    int beg = offs[n], end = offs[n + 1];
    float inv[HEADS];
    #pragma unroll
    for (int h = 0; h < HEADS; ++h) inv[h] = 1.f / (s[n*4 + h] + 1e-16f);
    float acc[HEADS] = {0.f, 0.f, 0.f, 0.f};
    for (int idx = beg; idx < end; ++idx) {
        int e  = order[idx];
        int sn = src[e];
        const float* ftp = ft + (size_t)sn * 512;
        #pragma unroll
        for (int h = 0; h < HEADS; ++h) {
            float a = ex[(size_t)e*4 + h] * inv[h];
            acc[h] = fmaf(a, ftp[h*128 + j], acc[h]);
        }
    }
    #pragma unroll
    for (int h = 0; h < HEADS; ++h)
        out[(size_t)n*512 + h*128 + j] = acc[h];
}

// ---------------------------------------------------------------------------
extern "C" void kernel_launch(void* const* d_in, const int* in_sizes, int n_in,
                              void* d_out, int out_size, void* d_ws, size_t ws_size,
                              hipStream_t stream)
{
    const float* feat     = (const float*)d_in[0];
    const float* fc       = (const float*)d_in[1];
    const float* attn_l   = (const float*)d_in[2];
    const float* attn_r   = (const float*)d_in[3];
    const float* edge_emb = (const float*)d_in[4];
    const float* w_e      = (const float*)d_in[5];
    const float* attn_e   = (const float*)d_in[6];
    const int*   e_feat   = (const int*)d_in[7];
    const int*   src      = (const int*)d_in[8];
    const int*   dst      = (const int*)d_in[9];

    int N = in_sizes[0] / (N_NTYPE * IN_F);   // 20000
    int E = in_sizes[7];                       // 320000
    float* out = (float*)d_out;

    // carve workspace (all regions fully initialized before read)
    char* w = (char*)d_ws;
    auto carve = [&](size_t bytes) -> char* {
        char* r = w;
        w += (bytes + 255) / 256 * 256;
        return r;
    };
    float* ft    = (float*)carve((size_t)N * 512 * sizeof(float));
    float* el    = (float*)carve((size_t)N * 4 * sizeof(float));
    float* er    = (float*)carve((size_t)N * 4 * sizeof(float));
    float* ee    = (float*)carve(N_ETYPE * HEADS * sizeof(float));
    float* ex    = (float*)carve((size_t)E * 4 * sizeof(float));
    float* ssum  = (float*)carve((size_t)N * 4 * sizeof(float));
    int*   cnt   = (int*)carve((size_t)N * sizeof(int));
    int*   offs  = (int*)carve((size_t)(N + 1) * sizeof(int));
    int*   pos   = (int*)carve((size_t)N * sizeof(int));
    int*   order = (int*)carve((size_t)E * sizeof(int));

    hipMemsetAsync(cnt,  0, (size_t)N * sizeof(int), stream);
    hipMemsetAsync(ssum, 0, (size_t)N * 4 * sizeof(float), stream);

    k_node<<<(N + NPB - 1) / NPB, 128, 0, stream>>>(feat, fc, attn_l, attn_r, ft, el, er, N);
    k_ee<<<1, 256, 0, stream>>>(edge_emb, w_e, attn_e, ee);
    k_edge<<<(E + 255) / 256, 256, 0, stream>>>(src, dst, e_feat, el, er, ee, ex, ssum, cnt, E);
    k_scan<<<1, 256, 0, stream>>>(cnt, offs, pos, N);
    k_scatter<<<(E + 255) / 256, 256, 0, stream>>>(dst, pos, order, E);
    k_agg<<<N, 128, 0, stream>>>(offs, order, src, ex, ssum, ft, out);
}

// Round 2
// 262.096 us; speedup vs baseline: 1.6744x; 1.6744x over previous
//
#include <hip/hip_runtime.h>
#include <hip/hip_bf16.h>

// slotGATConv: N=20000 nodes, E=320000 edges, 4 ntypes x 64 in, 4 heads x 32 out,
// 8 edge types x 64 edge feats. Inputs f32, output f32. ft staged as bf16.

#define N_NTYPE 4
#define IN_F    64
#define OUT_F   32
#define HEADS   4
#define EDGE_F  64
#define N_ETYPE 8
#define SLOPE   0.2f
#define NPB     8     // nodes per block in k_node
#define CH      64    // edge chunk in k_agg

// ---------------- Phase A: per-node linear + attention dots + dst histogram
// ft[n, h, t*32+o] = sum_i feat[n, t*64+i] * fc[t, i, h*32+o]   (stored bf16)
// el[n,h] = sum_k ft[n,h,k]*attn_l[h,k];  er likewise (f32).
__global__ __launch_bounds__(256) void k_node(
    const float4* __restrict__ feat4, const float* __restrict__ fc,
    const float* __restrict__ attn_l, const float* __restrict__ attn_r,
    __hip_bfloat16* __restrict__ ftb, float* __restrict__ el, float* __restrict__ er,
    const int* __restrict__ dst, int* __restrict__ cnt, int N, int E)
{
    int tid = threadIdx.x;
    int n0  = blockIdx.x * NPB;

    // folded dst-histogram: this grid (2500x256) covers E=320000
    int eid = blockIdx.x * 256 + tid;
    if (eid < E) atomicAdd(&cnt[dst[eid]], 1);

    __shared__ float4 sf4[NPB * 64];   // 8 nodes x 256 f32
    sf4[tid]       = feat4[(size_t)n0 * 64 + tid];
    sf4[tid + 256] = feat4[(size_t)n0 * 64 + tid + 256];
    __syncthreads();

    int tp = tid >> 7;       // half: handles t in {2tp, 2tp+1}
    int j  = tid & 127;      // h*32+o

    float acc0[NPB], acc1[NPB];
    #pragma unroll
    for (int nn = 0; nn < NPB; ++nn) { acc0[nn] = 0.f; acc1[nn] = 0.f; }

    // tt = 0
    {
        int t = tp * 2;
        const float* fcol = fc + (size_t)t * IN_F * 128 + j;
        #pragma unroll 4
        for (int i4 = 0; i4 < 16; ++i4) {
            float w0 = fcol[(i4*4+0)*128];
            float w1 = fcol[(i4*4+1)*128];
            float w2 = fcol[(i4*4+2)*128];
            float w3 = fcol[(i4*4+3)*128];
            #pragma unroll
            for (int nn = 0; nn < NPB; ++nn) {
                float4 f = sf4[nn*64 + t*16 + i4];
                float a = acc0[nn];
                a = fmaf(f.x, w0, a); a = fmaf(f.y, w1, a);
                a = fmaf(f.z, w2, a); a = fmaf(f.w, w3, a);
                acc0[nn] = a;
            }
        }
    }
    // tt = 1
    {
        int t = tp * 2 + 1;
        const float* fcol = fc + (size_t)t * IN_F * 128 + j;
        #pragma unroll 4
        for (int i4 = 0; i4 < 16; ++i4) {
            float w0 = fcol[(i4*4+0)*128];
            float w1 = fcol[(i4*4+1)*128];
            float w2 = fcol[(i4*4+2)*128];
            float w3 = fcol[(i4*4+3)*128];
            #pragma unroll
            for (int nn = 0; nn < NPB; ++nn) {
                float4 f = sf4[nn*64 + t*16 + i4];
                float a = acc1[nn];
                a = fmaf(f.x, w0, a); a = fmaf(f.y, w1, a);
                a = fmaf(f.z, w2, a); a = fmaf(f.w, w3, a);
                acc1[nn] = a;
            }
        }
    }

    int h = j >> 5, o = j & 31;
    int t0 = tp * 2, t1 = tp * 2 + 1;

    // store ft (bf16)
    #pragma unroll
    for (int nn = 0; nn < NPB; ++nn) {
        ftb[(size_t)(n0+nn)*512 + h*128 + t0*32 + o] = __float2bfloat16(acc0[nn]);
        ftb[(size_t)(n0+nn)*512 + h*128 + t1*32 + o] = __float2bfloat16(acc1[nn]);
    }

    // attention partial dots (this thread's two t-slices)
    float al0 = attn_l[h*128 + t0*32 + o];
    float al1 = attn_l[h*128 + t1*32 + o];
    float ar0 = attn_r[h*128 + t0*32 + o];
    float ar1 = attn_r[h*128 + t1*32 + o];

    __shared__ float pbuf[2][2][NPB][4];   // [l/r][tp][nn][h]
    #pragma unroll
    for (int nn = 0; nn < NPB; ++nn) {
        float pl = acc0[nn]*al0 + acc1[nn]*al1;
        float pr = acc0[nn]*ar0 + acc1[nn]*ar1;
        #pragma unroll
        for (int m = 16; m >= 1; m >>= 1) {
            pl += __shfl_xor(pl, m);
            pr += __shfl_xor(pr, m);
        }
        if (o == 0) { pbuf[0][tp][nn][h] = pl; pbuf[1][tp][nn][h] = pr; }
    }
    __syncthreads();
    if (tid < NPB*4) {
        int nn = tid >> 2, hh = tid & 3;
        el[(size_t)(n0+nn)*4 + hh] = pbuf[0][0][nn][hh] + pbuf[0][1][nn][hh];
        er[(size_t)(n0+nn)*4 + hh] = pbuf[1][0][nn][hh] + pbuf[1][1][nn][hh];
    }
}

// ---------------- Phase B: ee table (8x4) + exclusive scan of counts -------
__global__ __launch_bounds__(1024) void k_scan(
    const int* __restrict__ cnt, int* __restrict__ offs, int* __restrict__ pos, int N,
    const float* __restrict__ edge_emb, const float* __restrict__ w_e,
    const float* __restrict__ attn_e, float* __restrict__ ee_type)
{
    int tid = threadIdx.x;

    // ee[et,h] = sum_f (sum_c emb[et,c]*w_e[c, h*64+f]) * attn_e[h,f]
    if (tid < 256) {
        int et = tid >> 5, lane = tid & 31;
        float p[HEADS] = {0.f, 0.f, 0.f, 0.f};
        for (int f0 = 0; f0 < 2; ++f0) {
            int f = lane + f0*32;
            #pragma unroll
            for (int h = 0; h < HEADS; ++h) {
                float proj = 0.f;
                for (int c = 0; c < EDGE_F; ++c)
                    proj = fmaf(edge_emb[et*EDGE_F + c], w_e[c*256 + h*64 + f], proj);
                p[h] = fmaf(proj, attn_e[h*64 + f], p[h]);
            }
        }
        #pragma unroll
        for (int m = 16; m >= 1; m >>= 1)
            #pragma unroll
            for (int h = 0; h < HEADS; ++h) p[h] += __shfl_xor(p[h], m);
        if (lane == 0)
            #pragma unroll
            for (int h = 0; h < HEADS; ++h) ee_type[et*4 + h] = p[h];
    }

    // exclusive scan over cnt[0..N)
    int chunk = (N + 1023) / 1024;
    int start = min(tid * chunk, N);
    int end   = min(start + chunk, N);
    int tsum = 0;
    for (int i = start; i < end; ++i) tsum += cnt[i];
    int lane = tid & 63, wv = tid >> 6;
    int v = tsum;
    #pragma unroll
    for (int d = 1; d < 64; d <<= 1) {
        int u = __shfl_up(v, d);
        if (lane >= d) v += u;
    }
    __shared__ int wsum[16];
    if (lane == 63) wsum[wv] = v;
    __syncthreads();
    int base = 0;
    for (int w = 0; w < wv; ++w) base += wsum[w];
    int run = base + v - tsum;
    for (int i = start; i < end; ++i) {
        offs[i] = run; pos[i] = run; run += cnt[i];
    }
    if (tid == 1023) offs[N] = run;
}

// ---------------- Phase C: scatter (src, etype) into CSR order -------------
__global__ void k_scatter(const int* __restrict__ src, const int* __restrict__ dst,
                          const int* __restrict__ ef, int* __restrict__ pos,
                          int* __restrict__ srcs, int* __restrict__ efs, int E)
{
    int e = blockIdx.x * 256 + threadIdx.x;
    if (e >= E) return;
    int p = atomicAdd(&pos[dst[e]], 1);
    srcs[p] = src[e];
    efs[p]  = ef[e];
}

// ---------------- Phase D: fused logits+softmax+aggregation per dst --------
__global__ __launch_bounds__(128) void k_agg(
    const int* __restrict__ offs, const int* __restrict__ srcs,
    const int* __restrict__ efs,
    const float4* __restrict__ el4, const float4* __restrict__ er4,
    const float* __restrict__ ee_type,
    const __hip_bfloat16* __restrict__ ftb, float* __restrict__ out)
{
    int n = blockIdx.x, j = threadIdx.x;   // j in [0,128): h*... out slot within head-major row
    int beg = offs[n], end = offs[n+1];

    __shared__ int   ssn[CH];
    __shared__ float sx[CH][HEADS];
    __shared__ float see[N_ETYPE*HEADS];
    if (j < N_ETYPE*HEADS) see[j] = ee_type[j];

    float4 ern = er4[n];
    float acc[HEADS] = {0.f, 0.f, 0.f, 0.f};
    float ssp[HEADS] = {0.f, 0.f, 0.f, 0.f};

    for (int c0 = beg; c0 < end; c0 += CH) {
        int m = min(CH, end - c0);
        __syncthreads();
        if (j < m) {
            int sn = srcs[c0 + j];
            int t  = efs[c0 + j];
            ssn[j] = sn;
            float4 l4 = el4[sn];
            float lv0 = l4.x + ern.x + see[t*4+0];
            float lv1 = l4.y + ern.y + see[t*4+1];
            float lv2 = l4.z + ern.z + see[t*4+2];
            float lv3 = l4.w + ern.w + see[t*4+3];
            lv0 = (lv0 > 0.f) ? lv0 : SLOPE*lv0;
            lv1 = (lv1 > 0.f) ? lv1 : SLOPE*lv1;
            lv2 = (lv2 > 0.f) ? lv2 : SLOPE*lv2;
            lv3 = (lv3 > 0.f) ? lv3 : SLOPE*lv3;
            float x0 = __expf(lv0), x1 = __expf(lv1);
            float x2 = __expf(lv2), x3 = __expf(lv3);
            sx[j][0] = x0; sx[j][1] = x1; sx[j][2] = x2; sx[j][3] = x3;
            ssp[0] += x0; ssp[1] += x1; ssp[2] += x2; ssp[3] += x3;
        }
        __syncthreads();
        #pragma unroll 2
        for (int k = 0; k < m; ++k) {
            int sn = ssn[k];
            const __hip_bfloat16* fp = ftb + (size_t)sn*512 + j;
            #pragma unroll
            for (int h = 0; h < HEADS; ++h) {
                float fv = __bfloat162float(fp[h*128]);
                acc[h] = fmaf(sx[k][h], fv, acc[h]);
            }
        }
    }

    // reduce softmax denominator across all 128 threads
    #pragma unroll
    for (int m2 = 32; m2 >= 1; m2 >>= 1)
        #pragma unroll
        for (int h = 0; h < HEADS; ++h) ssp[h] += __shfl_xor(ssp[h], m2);
    __shared__ float swsum[2][HEADS];
    if ((j & 63) == 0) {
        int w = j >> 6;
        #pragma unroll
        for (int h = 0; h < HEADS; ++h) swsum[w][h] = ssp[h];
    }
    __syncthreads();
    #pragma unroll
    for (int h = 0; h < HEADS; ++h) {
        float inv = 1.f / (swsum[0][h] + swsum[1][h] + 1e-16f);
        out[(size_t)n*512 + h*128 + j] = acc[h] * inv;
    }
}

// ---------------------------------------------------------------------------
extern "C" void kernel_launch(void* const* d_in, const int* in_sizes, int n_in,
                              void* d_out, int out_size, void* d_ws, size_t ws_size,
                              hipStream_t stream)
{
    const float* feat     = (const float*)d_in[0];
    const float* fc       = (const float*)d_in[1];
    const float* attn_l   = (const float*)d_in[2];
    const float* attn_r   = (const float*)d_in[3];
    const float* edge_emb = (const float*)d_in[4];
    const float* w_e      = (const float*)d_in[5];
    const float* attn_e   = (const float*)d_in[6];
    const int*   e_feat   = (const int*)d_in[7];
    const int*   src      = (const int*)d_in[8];
    const int*   dst      = (const int*)d_in[9];

    int N = in_sizes[0] / (N_NTYPE * IN_F);   // 20000
    int E = in_sizes[7];                       // 320000
    float* out = (float*)d_out;

    char* w = (char*)d_ws;
    auto carve = [&](size_t bytes) -> char* {
        char* r = w;
        w += (bytes + 255) / 256 * 256;
        return r;
    };
    __hip_bfloat16* ftb = (__hip_bfloat16*)carve((size_t)N * 512 * sizeof(__hip_bfloat16));
    float* el    = (float*)carve((size_t)N * 4 * sizeof(float));
    float* er    = (float*)carve((size_t)N * 4 * sizeof(float));
    float* ee    = (float*)carve(N_ETYPE * HEADS * sizeof(float));
    int*   cnt   = (int*)carve((size_t)N * sizeof(int));
    int*   offs  = (int*)carve((size_t)(N + 1) * sizeof(int));
    int*   pos   = (int*)carve((size_t)N * sizeof(int));
    int*   srcs  = (int*)carve((size_t)E * sizeof(int));
    int*   efs   = (int*)carve((size_t)E * sizeof(int));

    hipMemsetAsync(cnt, 0, (size_t)N * sizeof(int), stream);

    k_node<<<N / NPB, 256, 0, stream>>>((const float4*)feat, fc, attn_l, attn_r,
                                        ftb, el, er, dst, cnt, N, E);
    k_scan<<<1, 1024, 0, stream>>>(cnt, offs, pos, N, edge_emb, w_e, attn_e, ee);
    k_scatter<<<(E + 255) / 256, 256, 0, stream>>>(src, dst, e_feat, pos, srcs, efs, E);
    k_agg<<<N, 128, 0, stream>>>(offs, srcs, efs, (const float4*)el, (const float4*)er,
                                 ee, ftb, out);
}

// Round 8
// 224.670 us; speedup vs baseline: 1.9533x; 1.1666x over previous
//
#include <hip/hip_runtime.h>
#include <hip/hip_bf16.h>

// slotGATConv: N=20000, E=320000, 4 ntypes x 64 in, 4 heads x 32 out,
// 8 edge types x 64 edge feats. Inputs f32, output f32. ft staged bf16 as
// ftb[n][slot][h], slot = t*32+o in [0,128), h in [0,4)  (8B per slot).

#define N_NTYPE 4
#define IN_F    64
#define HEADS   4
#define EDGE_F  64
#define N_ETYPE 8
#define SLOPE   0.2f
#define NPB     16    // nodes per block in k_node
#define ANW     4     // nodes (waves) per block in k_agg

__device__ __forceinline__ float bf2f(unsigned short u) {
    return __uint_as_float((unsigned int)u << 16);
}

// ---------------- k_prep: zero cnt + ee table (8x4) ------------------------
// ee[et,h] = sum_f (sum_c emb[et,c]*w_e[c,h*64+f]) * attn_e[h,f]
__global__ __launch_bounds__(256) void k_prep(
    const float* __restrict__ edge_emb, const float* __restrict__ w_e,
    const float* __restrict__ attn_e, float* __restrict__ ee_tab,
    int* __restrict__ cnt, int N)
{
    int tid = threadIdx.x;
    int4 z = {0, 0, 0, 0};
    for (int i = tid * 4; i + 3 < N; i += 1024)
        *(int4*)&cnt[i] = z;

    __shared__ float semb[N_ETYPE * EDGE_F];
    semb[tid]       = edge_emb[tid];
    semb[tid + 256] = edge_emb[tid + 256];
    __syncthreads();

    int h = tid >> 6, f = tid & 63;          // wave h, lane f
    float proj[N_ETYPE] = {0.f,0.f,0.f,0.f,0.f,0.f,0.f,0.f};
    for (int c = 0; c < EDGE_F; ++c) {
        float w = w_e[c * 256 + h * 64 + f];   // coalesced
        #pragma unroll
        for (int et = 0; et < N_ETYPE; ++et)
            proj[et] = fmaf(semb[et * 64 + c], w, proj[et]);
    }
    float ae = attn_e[h * 64 + f];
    #pragma unroll
    for (int et = 0; et < N_ETYPE; ++et) {
        float p = proj[et] * ae;
        #pragma unroll
        for (int m = 32; m >= 1; m >>= 1) p += __shfl_xor(p, m);
        if (f == 0) ee_tab[et * 4 + h] = p;
    }
}

// ---------------- k_node: per-node linear + attn dots + dst histogram ------
// thread j (0..127, within tp-half): o = j>>2, h = j&3, output col = h*32+o.
// ftb store index = n*512 + t*128 + j  (contiguous over j).
__global__ __launch_bounds__(256, 4) void k_node(
    const float4* __restrict__ feat4, const float* __restrict__ fc,
    const float* __restrict__ attn_l, const float* __restrict__ attn_r,
    __hip_bfloat16* __restrict__ ftb, float* __restrict__ el, float* __restrict__ er,
    const int* __restrict__ dst, int* __restrict__ cnt, int N, int E)
{
    int tid = threadIdx.x;
    int n0  = blockIdx.x * NPB;

    int eid = blockIdx.x * 256 + tid;        // grid*256 == E exactly
    if (eid < E) atomicAdd(&cnt[dst[eid]], 1);

    __shared__ float4 sf4[NPB * 64];         // 16 nodes x 256 f32 = 16KB
    #pragma unroll
    for (int q = 0; q < 4; ++q)
        sf4[tid + q * 256] = feat4[(size_t)n0 * 64 + tid + q * 256];
    __syncthreads();

    int tp = tid >> 7, j = tid & 127;
    int o = j >> 2, h = j & 3;
    int col = h * 32 + o;
    int t0 = tp * 2, t1 = t0 + 1;

    float acc0[NPB], acc1[NPB];
    #pragma unroll
    for (int nn = 0; nn < NPB; ++nn) { acc0[nn] = 0.f; acc1[nn] = 0.f; }

    const float* fcA = fc + (size_t)t0 * IN_F * 128 + col;
    const float* fcB = fc + (size_t)t1 * IN_F * 128 + col;

    for (int i4 = 0; i4 < 16; ++i4) {
        float wa0 = fcA[(i4*4+0)*128], wa1 = fcA[(i4*4+1)*128];
        float wa2 = fcA[(i4*4+2)*128], wa3 = fcA[(i4*4+3)*128];
        #pragma unroll
        for (int nn = 0; nn < NPB; ++nn) {
            float4 f = sf4[nn*64 + t0*16 + i4];
            float a = acc0[nn];
            a = fmaf(f.x, wa0, a); a = fmaf(f.y, wa1, a);
            a = fmaf(f.z, wa2, a); a = fmaf(f.w, wa3, a);
            acc0[nn] = a;
        }
        float wb0 = fcB[(i4*4+0)*128], wb1 = fcB[(i4*4+1)*128];
        float wb2 = fcB[(i4*4+2)*128], wb3 = fcB[(i4*4+3)*128];
        #pragma unroll
        for (int nn = 0; nn < NPB; ++nn) {
            float4 f = sf4[nn*64 + t1*16 + i4];
            float a = acc1[nn];
            a = fmaf(f.x, wb0, a); a = fmaf(f.y, wb1, a);
            a = fmaf(f.z, wb2, a); a = fmaf(f.w, wb3, a);
            acc1[nn] = a;
        }
    }

    // stores: contiguous bf16 over j
    #pragma unroll
    for (int nn = 0; nn < NPB; ++nn) {
        size_t b = (size_t)(n0 + nn) * 512;
        ftb[b + t0*128 + j] = __float2bfloat16(acc0[nn]);
        ftb[b + t1*128 + j] = __float2bfloat16(acc1[nn]);
    }

    // attention dots
    float al0 = attn_l[h*128 + t0*32 + o], al1 = attn_l[h*128 + t1*32 + o];
    float ar0 = attn_r[h*128 + t0*32 + o], ar1 = attn_r[h*128 + t1*32 + o];

    __shared__ float pbuf[2][4][NPB][4];     // [l/r][wave][nn][h] = 2KB
    int wid = tid >> 6, lane = tid & 63;
    #pragma unroll
    for (int nn = 0; nn < NPB; ++nn) {
        float pl = acc0[nn]*al0 + acc1[nn]*al1;
        float pr = acc0[nn]*ar0 + acc1[nn]*ar1;
        #pragma unroll
        for (int m = 4; m <= 32; m <<= 1) {
            pl += __shfl_xor(pl, m);
            pr += __shfl_xor(pr, m);
        }
        if (lane < 4) { pbuf[0][wid][nn][lane] = pl; pbuf[1][wid][nn][lane] = pr; }
    }
    __syncthreads();
    if (tid < NPB * 4) {
        int nn = tid >> 2, hh = tid & 3;
        float sl = 0.f, sr = 0.f;
        #pragma unroll
        for (int w = 0; w < 4; ++w) { sl += pbuf[0][w][nn][hh]; sr += pbuf[1][w][nn][hh]; }
        el[(size_t)(n0+nn)*4 + hh] = sl;
        er[(size_t)(n0+nn)*4 + hh] = sr;
    }
}

// ---------------- k_scan: exclusive scan of cnt (single block, int4) -------
__global__ __launch_bounds__(1024) void k_scan(
    const int* __restrict__ cnt, int* __restrict__ offs, int* __restrict__ pos, int N)
{
    int tid = threadIdx.x;
    int chunk = (((N + 1023) / 1024) + 3) & ~3;     // 20 for N=20000
    int start = min(tid * chunk, N);
    int end   = min(start + chunk, N);

    int tsum = 0;
    int i = start;
    for (; i + 3 < end; i += 4) {
        int4 c = *(const int4*)&cnt[i];
        tsum += c.x + c.y + c.z + c.w;
    }
    for (; i < end; ++i) tsum += cnt[i];

    int lane = tid & 63, wv = tid >> 6;
    int v = tsum;
    #pragma unroll
    for (int d = 1; d < 64; d <<= 1) {
        int u = __shfl_up(v, d);
        if (lane >= d) v += u;
    }
    __shared__ int wsum[16];
    if (lane == 63) wsum[wv] = v;
    __syncthreads();
    int base = 0;
    for (int w = 0; w < wv; ++w) base += wsum[w];
    int run = base + v - tsum;

    i = start;
    for (; i + 3 < end; i += 4) {
        int4 c = *(const int4*)&cnt[i];
        int4 ov;
        ov.x = run; run += c.x;
        ov.y = run; run += c.y;
        ov.z = run; run += c.z;
        ov.w = run; run += c.w;
        *(int4*)&offs[i] = ov;
        *(int4*)&pos[i]  = ov;
    }
    for (; i < end; ++i) { offs[i] = run; pos[i] = run; run += cnt[i]; }
    if (end == N && start < N) offs[N] = run;       // == E
}

// ---------------- k_scatter: packed (src | etype<<24) into CSR order -------
__global__ void k_scatter(const int* __restrict__ src, const int* __restrict__ dst,
                          const int* __restrict__ ef, int* __restrict__ pos,
                          unsigned int* __restrict__ pay, int E)
{
    int e = blockIdx.x * 256 + threadIdx.x;
    if (e >= E) return;
    int p = atomicAdd(&pos[dst[e]], 1);
    pay[p] = (unsigned int)src[e] | ((unsigned int)ef[e] << 24);
}

// ---------------- k_agg: wave-per-node fused softmax + aggregation ---------
__global__ __launch_bounds__(256) void k_agg(
    const int* __restrict__ offs, const unsigned int* __restrict__ pay,
    const float4* __restrict__ el4, const float4* __restrict__ er4,
    const float4* __restrict__ ee4t,
    const __hip_bfloat16* __restrict__ ftb, float* __restrict__ out)
{
    int tid = threadIdx.x, wid = tid >> 6, lane = tid & 63;
    int n = blockIdx.x * ANW + wid;

    __shared__ float4 sx4[ANW][64];
    __shared__ int    ssn[ANW][64];
    __shared__ float4 see4[N_ETYPE];
    if (tid < N_ETYPE) see4[tid] = ee4t[tid];
    __syncthreads();

    int beg = offs[n], end = offs[n + 1];
    float4 ern = er4[n];
    float a0=0,a1=0,a2=0,a3=0,a4=0,a5=0,a6=0,a7=0;
    float d0=0,d1=0,d2=0,d3=0;

    for (int c0 = beg; c0 < end; c0 += 64) {
        int m = min(64, end - c0);
        if (lane < m) {
            unsigned int pk = pay[c0 + lane];
            int sn = (int)(pk & 0xFFFFFFu);
            int et = (int)(pk >> 24);
            ssn[wid][lane] = sn;
            float4 l4 = el4[sn];
            float4 e4 = see4[et];
            float v0 = l4.x + ern.x + e4.x;
            float v1 = l4.y + ern.y + e4.y;
            float v2 = l4.z + ern.z + e4.z;
            float v3 = l4.w + ern.w + e4.w;
            v0 = (v0 > 0.f) ? v0 : SLOPE * v0;
            v1 = (v1 > 0.f) ? v1 : SLOPE * v1;
            v2 = (v2 > 0.f) ? v2 : SLOPE * v2;
            v3 = (v3 > 0.f) ? v3 : SLOPE * v3;
            float x0 = __expf(v0), x1 = __expf(v1);
            float x2 = __expf(v2), x3 = __expf(v3);
            sx4[wid][lane] = make_float4(x0, x1, x2, x3);
            d0 += x0; d1 += x1; d2 += x2; d3 += x3;
        }
        __builtin_amdgcn_wave_barrier();   // intra-wave LDS RAW: DS pipe is in-order
        for (int k = 0; k < m; ++k) {
            int sn = ssn[wid][k];
            float4 x = sx4[wid][k];
            const ushort4* fp = (const ushort4*)(ftb + (size_t)sn * 512);
            ushort4 f0 = fp[lane];
            ushort4 f1 = fp[lane + 64];
            a0 = fmaf(x.x, bf2f(f0.x), a0);
            a1 = fmaf(x.y, bf2f(f0.y), a1);
            a2 = fmaf(x.z, bf2f(f0.z), a2);
            a3 = fmaf(x.w, bf2f(f0.w), a3);
            a4 = fmaf(x.x, bf2f(f1.x), a4);
            a5 = fmaf(x.y, bf2f(f1.y), a5);
            a6 = fmaf(x.z, bf2f(f1.z), a6);
            a7 = fmaf(x.w, bf2f(f1.w), a7);
        }
        __builtin_amdgcn_wave_barrier();
    }

    #pragma unroll
    for (int m2 = 1; m2 <= 32; m2 <<= 1) {
        d0 += __shfl_xor(d0, m2); d1 += __shfl_xor(d1, m2);
        d2 += __shfl_xor(d2, m2); d3 += __shfl_xor(d3, m2);
    }
    float i0 = 1.f/(d0 + 1e-16f), i1 = 1.f/(d1 + 1e-16f);
    float i2 = 1.f/(d2 + 1e-16f), i3 = 1.f/(d3 + 1e-16f);

    size_t ob = (size_t)n * 512;
    out[ob + 0*128 + lane]      = a0 * i0;
    out[ob + 1*128 + lane]      = a1 * i1;
    out[ob + 2*128 + lane]      = a2 * i2;
    out[ob + 3*128 + lane]      = a3 * i3;
    out[ob + 0*128 + 64 + lane] = a4 * i0;
    out[ob + 1*128 + 64 + lane] = a5 * i1;
    out[ob + 2*128 + 64 + lane] = a6 * i2;
    out[ob + 3*128 + 64 + lane] = a7 * i3;
}

// ---------------------------------------------------------------------------
extern "C" void kernel_launch(void* const* d_in, const int* in_sizes, int n_in,
                              void* d_out, int out_size, void* d_ws, size_t ws_size,
                              hipStream_t stream)
{
    const float* feat     = (const float*)d_in[0];
    const float* fc       = (const float*)d_in[1];
    const float* attn_l   = (const float*)d_in[2];
    const float* attn_r   = (const float*)d_in[3];
    const float* edge_emb = (const float*)d_in[4];
    const float* w_e      = (const float*)d_in[5];
    const float* attn_e   = (const float*)d_in[6];
    const int*   e_feat   = (const int*)d_in[7];
    const int*   src      = (const int*)d_in[8];
    const int*   dst      = (const int*)d_in[9];

    int N = in_sizes[0] / (N_NTYPE * IN_F);   // 20000
    int E = in_sizes[7];                       // 320000
    float* out = (float*)d_out;

    char* w = (char*)d_ws;
    auto carve = [&](size_t bytes) -> char* {
        char* r = w;
        w += (bytes + 255) / 256 * 256;
        return r;
    };
    __hip_bfloat16* ftb = (__hip_bfloat16*)carve((size_t)N * 512 * sizeof(__hip_bfloat16));
    float* el    = (float*)carve((size_t)N * 4 * sizeof(float));
    float* er    = (float*)carve((size_t)N * 4 * sizeof(float));
    float* ee    = (float*)carve(N_ETYPE * HEADS * sizeof(float));
    int*   cnt   = (int*)carve((size_t)N * sizeof(int));
    int*   offs  = (int*)carve((size_t)(N + 1) * sizeof(int));
    int*   pos   = (int*)carve((size_t)N * sizeof(int));
    unsigned int* pay = (unsigned int*)carve((size_t)E * sizeof(unsigned int));

    k_prep<<<1, 256, 0, stream>>>(edge_emb, w_e, attn_e, ee, cnt, N);
    k_node<<<(N + NPB - 1) / NPB, 256, 0, stream>>>(
        (const float4*)feat, fc, attn_l, attn_r, ftb, el, er, dst, cnt, N, E);
    k_scan<<<1, 1024, 0, stream>>>(cnt, offs, pos, N);
    k_scatter<<<(E + 255) / 256, 256, 0, stream>>>(src, dst, e_feat, pos, pay, E);
    k_agg<<<(N + ANW - 1) / ANW, 256, 0, stream>>>(
        offs, pay, (const float4*)el, (const float4*)er, (const float4*)ee, ftb, out);
}